// Round 1
// baseline (622.863 us; speedup 1.0000x reference)
//
#include <hip/hip_runtime.h>
#include <hip/hip_bf16.h>
#include <cstdint>
#include <cstddef>

// Problem constants
// B=8, W=32, H=32, C=64, NH=8, P=64, M=32, AH=512, S=W*H=1024
#define SB 8
#define SW 32
#define SH 32
#define SC 64
#define SNH 8
#define SS 1024
#define SAH 512

// ---------------------------------------------------------------------------
// Kernel 1: Q/K projection.  out[(b*8+n)*1024+s][d] = hid[b,s,:] @ w[a,:] + bias[a]
// grid (256, 2): x = 32-row tile of flattened (B*S); y selects Q (0) or K (1).
// ---------------------------------------------------------------------------
__global__ __launch_bounds__(256) void qk_proj(
    const float* __restrict__ hid,
    const float* __restrict__ wq, const float* __restrict__ bq,
    const float* __restrict__ wk, const float* __restrict__ bk,
    float* __restrict__ Qw, float* __restrict__ Kw)
{
    const float* w   = blockIdx.y ? wk : wq;
    const float* bb  = blockIdx.y ? bk : bq;
    float* outp      = blockIdx.y ? Kw : Qw;
    const int tile = blockIdx.x;            // rows tile*32 .. +31 of (B*S)
    const int tid  = threadIdx.x;

    __shared__ float hs[32][64];
    for (int x = tid; x < 32 * 64; x += 256)
        hs[x >> 6][x & 63] = hid[(size_t)tile * 2048 + x];
    __syncthreads();

    const int a0 = tid, a1 = tid + 256;     // output columns (a = n*64+d)
    float acc0[32], acc1[32];
    const float bv0 = bb[a0], bv1 = bb[a1];
#pragma unroll
    for (int r = 0; r < 32; ++r) { acc0[r] = bv0; acc1[r] = bv1; }

    for (int c = 0; c < 64; c += 4) {
        const float4 w0 = *(const float4*)&w[a0 * 64 + c];
        const float4 w1 = *(const float4*)&w[a1 * 64 + c];
#pragma unroll
        for (int r = 0; r < 32; ++r) {
            const float4 h4 = *(const float4*)&hs[r][c];
            acc0[r] += h4.x * w0.x + h4.y * w0.y + h4.z * w0.z + h4.w * w0.w;
            acc1[r] += h4.x * w1.x + h4.y * w1.y + h4.z * w1.z + h4.w * w1.w;
        }
    }

    const int n0 = a0 >> 6, d0 = a0 & 63;
    const int n1 = a1 >> 6, d1 = a1 & 63;
#pragma unroll
    for (int r = 0; r < 32; ++r) {
        const int bs = tile * 32 + r;       // 32 | 1024, so tile never crosses batch
        const int b = bs >> 10, s = bs & 1023;
        outp[(((size_t)b * 8 + n0) * 1024 + s) * 64 + d0] = acc0[r];
        outp[(((size_t)b * 8 + n1) * 1024 + s) * 64 + d1] = acc1[r];
    }
}

// ---------------------------------------------------------------------------
// Kernel 2: positional score tables.
// posRow[n][j][l] = sum_p row_emb[l-j+31][p] * w_row[n][p]
// posCol[n][i][k] = sum_p col_emb[k-i+31][p] * w_col[n][p]
// grid 64 x 256 threads: 16384 outputs, one per thread.
// ---------------------------------------------------------------------------
__global__ __launch_bounds__(256) void pos_kernel(
    const float* __restrict__ row_emb, const float* __restrict__ col_emb,
    const float* __restrict__ w_row,   const float* __restrict__ w_col,
    float* __restrict__ posRow, float* __restrict__ posCol)
{
    const int idx = blockIdx.x * 256 + threadIdx.x;   // 0..16383
    const int which = idx >> 13;                      // 0 = row, 1 = col
    const int r = idx & 8191;
    const int n = r >> 10;
    const int j = (r >> 5) & 31;                      // query coord
    const int l = r & 31;                             // key coord
    const float* emb = which ? col_emb : row_emb;
    const float* wgt = which ? w_col : w_row;
    const int e = l - j + 31;                         // 0..62
    float acc = 0.f;
    for (int p = 0; p < 64; p += 4) {
        const float4 ev = *(const float4*)&emb[e * 64 + p];
        const float4 wv = *(const float4*)&wgt[n * 64 + p];
        acc += ev.x * wv.x + ev.y * wv.y + ev.z * wv.z + ev.w * wv.w;
    }
    (which ? posCol : posRow)[r] = acc;
}

// ---------------------------------------------------------------------------
// Kernel 3: fused attention with online softmax.
// grid (32, 8, 8) = (query-row i, head n, batch b); 256 threads = 4 waves.
// Block handles 32 queries (fixed i, j=0..31) over 32 K/V tiles of 32 keys.
// Thread (j = tid>>3, u = tid&7): scores for keys l = u+8k (k=0..3);
// PV for dims d = u*8 .. u*8+7 of query j.
// ---------------------------------------------------------------------------
__global__ __launch_bounds__(256) void attn_fused(
    const float* __restrict__ Qw, const float* __restrict__ Kw,
    const float* __restrict__ hid,
    const float* __restrict__ posRow, const float* __restrict__ posCol,
    float* __restrict__ headOut)
{
    const int i = blockIdx.x;
    const int n = blockIdx.y;
    const int b = blockIdx.z;
    const int tid = threadIdx.x;
    const int j = tid >> 3;
    const int u = tid & 7;

    __shared__ float Qs[32][68];   // pad 68: 16B-aligned rows, conflict-free
    __shared__ float Ks[32][68];
    __shared__ float Vs[32][68];
    __shared__ float Ps[32][36];
    __shared__ float rowS[32][32];

    // load Q tile (32 x 64) and row-pos table (32 x 32)
    {
        const float* Qbase = Qw + (((size_t)(b * 8 + n)) * 1024 + i * 32) * 64;
        for (int f = tid; f < 512; f += 256) {
            const float4 v = *(const float4*)&Qbase[f * 4];
            *(float4*)&Qs[f >> 4][(f & 15) * 4] = v;
        }
        const float* pr = posRow + n * 1024;
        for (int x = tid; x < 1024; x += 256)
            rowS[x >> 5][x & 31] = pr[x];
    }

    float m = -1e30f, lsum = 0.f;
    float acc[8];
#pragma unroll
    for (int dd = 0; dd < 8; ++dd) acc[dd] = 0.f;

    const float* Kbase = Kw + (((size_t)(b * 8 + n)) * 1024) * 64;
    const float* Vbase = hid + ((size_t)b * 1024) * 64;
    const float* pcb   = posCol + (n * 32 + i) * 32;

    for (int kt = 0; kt < 32; ++kt) {
        // prefetch K/V tile into registers (overlaps with prev PV phase)
        float4 kr[2], vr[2];
#pragma unroll
        for (int q = 0; q < 2; ++q) {
            const int f = tid + q * 256;
            kr[q] = *(const float4*)&Kbase[(size_t)kt * 2048 + f * 4];
            vr[q] = *(const float4*)&Vbase[(size_t)kt * 2048 + f * 4];
        }
        __syncthreads();                       // prev iteration done reading LDS
#pragma unroll
        for (int q = 0; q < 2; ++q) {
            const int f = tid + q * 256;
            *(float4*)&Ks[f >> 4][(f & 15) * 4] = kr[q];
            *(float4*)&Vs[f >> 4][(f & 15) * 4] = vr[q];
        }
        __syncthreads();                       // K/V visible

        const float pc = pcb[kt];

        // ---- scores: 4 keys per thread, d-outer for Q-reuse ----
        float dot[4] = {0.f, 0.f, 0.f, 0.f};
#pragma unroll
        for (int d = 0; d < 64; d += 4) {
            const float4 q4 = *(const float4*)&Qs[j][d];
#pragma unroll
            for (int kk = 0; kk < 4; ++kk) {
                const float4 k4 = *(const float4*)&Ks[u + kk * 8][d];
                dot[kk] += q4.x * k4.x + q4.y * k4.y + q4.z * k4.z + q4.w * k4.w;
            }
        }
        float sc[4];
#pragma unroll
        for (int kk = 0; kk < 4; ++kk)
            sc[kk] = dot[kk] * 0.125f + rowS[j][u + kk * 8] + pc;

        // ---- online softmax (8-lane group per query row) ----
        float tmax = fmaxf(fmaxf(sc[0], sc[1]), fmaxf(sc[2], sc[3]));
#pragma unroll
        for (int o = 1; o < 8; o <<= 1) tmax = fmaxf(tmax, __shfl_xor(tmax, o));
        const float mnew = fmaxf(m, tmax);
        const float r = __expf(m - mnew);
        float p[4], psum = 0.f;
#pragma unroll
        for (int kk = 0; kk < 4; ++kk) { p[kk] = __expf(sc[kk] - mnew); psum += p[kk]; }
#pragma unroll
        for (int o = 1; o < 8; o <<= 1) psum += __shfl_xor(psum, o);
        lsum = lsum * r + psum;
        m = mnew;
#pragma unroll
        for (int kk = 0; kk < 4; ++kk) Ps[j][u + kk * 8] = p[kk];
        __syncthreads();                       // Ps visible

        // ---- PV: thread owns dims du..du+7 of query j ----
        const int du = u * 8;
#pragma unroll
        for (int dd = 0; dd < 8; ++dd) acc[dd] *= r;
        for (int k = 0; k < 32; ++k) {
            const float pk = Ps[j][k];
            const float4 v0 = *(const float4*)&Vs[k][du];
            const float4 v1 = *(const float4*)&Vs[k][du + 4];
            acc[0] += pk * v0.x; acc[1] += pk * v0.y;
            acc[2] += pk * v0.z; acc[3] += pk * v0.w;
            acc[4] += pk * v1.x; acc[5] += pk * v1.y;
            acc[6] += pk * v1.z; acc[7] += pk * v1.w;
        }
        // next iteration's sync-before-LDS-write protects Vs/Ps
    }

    // epilogue: normalize, write headOut[b][s][n][d]  (a = n*64+d contiguous)
    const float inv = 1.0f / lsum;
    const int s = i * 32 + j;
    float* op = headOut + (((size_t)b * 1024 + s) * 8 + n) * 64 + u * 8;
    const float4 o0 = make_float4(acc[0] * inv, acc[1] * inv, acc[2] * inv, acc[3] * inv);
    const float4 o1 = make_float4(acc[4] * inv, acc[5] * inv, acc[6] * inv, acc[7] * inv);
    *(float4*)&op[0] = o0;
    *(float4*)&op[4] = o1;
}

// ---------------------------------------------------------------------------
// Kernel 4: final projection  out[row][d] = b_v[d] + sum_a ho[row][a]*w_v[d][a]
// grid 2048 x 256: block = 4 rows, one wave per row.
// ---------------------------------------------------------------------------
__global__ __launch_bounds__(256) void v_proj(
    const float* __restrict__ ho, const float* __restrict__ wv,
    const float* __restrict__ bv, float* __restrict__ out)
{
    const int tid = threadIdx.x;
    __shared__ float hs[4][512];
    for (int x = tid; x < 2048; x += 256)
        hs[x >> 9][x & 511] = ho[(size_t)blockIdx.x * 2048 + x];
    __syncthreads();

    const int w = tid >> 6;                  // wave -> row
    const int d = tid & 63;                  // output dim
    const int row = blockIdx.x * 4 + w;

    float acc = bv[d];
    const float4* wv4 = (const float4*)(wv + (size_t)d * 512);
    const float4* hs4 = (const float4*)hs[w];
#pragma unroll 8
    for (int a4 = 0; a4 < 128; ++a4) {
        const float4 wr = wv4[a4];
        const float4 hr = hs4[a4];
        acc += hr.x * wr.x + hr.y * wr.y + hr.z * wr.z + hr.w * wr.w;
    }
    out[(size_t)row * 64 + d] = acc;
}

// ---------------------------------------------------------------------------
extern "C" void kernel_launch(void* const* d_in, const int* in_sizes, int n_in,
                              void* d_out, int out_size, void* d_ws, size_t ws_size,
                              hipStream_t stream)
{
    const float* hid     = (const float*)d_in[0];
    // d_in[1] attention_mask: unused by the reference forward
    const float* row_emb = (const float*)d_in[2];
    const float* col_emb = (const float*)d_in[3];
    const float* w_row   = (const float*)d_in[4];
    const float* w_col   = (const float*)d_in[5];
    const float* w_q     = (const float*)d_in[6];
    const float* b_q     = (const float*)d_in[7];
    const float* w_k     = (const float*)d_in[8];
    const float* b_k     = (const float*)d_in[9];
    const float* w_v     = (const float*)d_in[10];
    const float* b_v     = (const float*)d_in[11];
    float* out = (float*)d_out;

    // workspace layout (f32): Q 16MB | K 16MB | posRow 32KB | posCol 32KB | headOut 16MB
    float* ws      = (float*)d_ws;
    float* Qw      = ws;
    float* Kw      = Qw + (size_t)SB * SNH * SS * SC;       // 4,194,304 floats
    float* posRow  = Kw + (size_t)SB * SNH * SS * SC;
    float* posCol  = posRow + SNH * SW * SW;                // 8192 floats
    float* headOut = posCol + SNH * SW * SW;                // 8*1024*512 floats

    qk_proj<<<dim3(256, 2), 256, 0, stream>>>(hid, w_q, b_q, w_k, b_k, Qw, Kw);
    pos_kernel<<<64, 256, 0, stream>>>(row_emb, col_emb, w_row, w_col, posRow, posCol);
    attn_fused<<<dim3(32, 8, 8), 256, 0, stream>>>(Qw, Kw, hid, posRow, posCol, headOut);
    v_proj<<<2048, 256, 0, stream>>>(headOut, w_v, b_v, out);
}

// Round 2
// 327.857 us; speedup vs baseline: 1.8998x; 1.8998x over previous
//
#include <hip/hip_runtime.h>
#include <hip/hip_bf16.h>
#include <cstdint>
#include <cstddef>

// B=8, W=32, H=32, C=64, NH=8, P=64, M=32, AH=512, S=W*H=1024
#define SB 8
#define SNH 8
#define SS 1024
#define SC 64

typedef __attribute__((ext_vector_type(8))) short bf16x8;
typedef __attribute__((ext_vector_type(4))) short bf16x4;
typedef __attribute__((ext_vector_type(4))) float f32x4;

#define INVLN2 1.44269504088896f
#define QSCALE (0.125f * INVLN2)

static __device__ __forceinline__ short f2bf(float f) {
    unsigned u = __builtin_bit_cast(unsigned, f);
    u = (u + 0x7fffu + ((u >> 16) & 1u)) >> 16;   // RNE
    return (short)u;
}

#if __has_builtin(__builtin_amdgcn_mfma_f32_16x16x16bf16_1k)
#define MFMA16(a, b, c) __builtin_amdgcn_mfma_f32_16x16x16bf16_1k((a), (b), (c), 0, 0, 0)
#else
static __device__ __forceinline__ f32x4 mfma16_asm(bf16x4 a, bf16x4 b, f32x4 c) {
    asm volatile("v_mfma_f32_16x16x16_bf16 %0, %1, %2, %0\n\ts_nop 7\n\ts_nop 7"
                 : "+v"(c) : "v"(a), "v"(b));
    return c;
}
#define MFMA16(a, b, c) mfma16_asm((a), (b), (c))
#endif

// ---------------------------------------------------------------------------
// Kernel 1: Q/K projection -> bf16.  Q pre-scaled by 0.125*log2(e).
// out[(b*8+n)*1024+s][d];  grid (256,2): y=0 -> Q, y=1 -> K.
// ---------------------------------------------------------------------------
__global__ __launch_bounds__(256) void qk_proj(
    const float* __restrict__ hid,
    const float* __restrict__ wq, const float* __restrict__ bq,
    const float* __restrict__ wk, const float* __restrict__ bk,
    short* __restrict__ Qw, short* __restrict__ Kw)
{
    const float* w  = blockIdx.y ? wk : wq;
    const float* bb = blockIdx.y ? bk : bq;
    short* outp     = blockIdx.y ? Kw : Qw;
    const float scl = blockIdx.y ? 1.0f : QSCALE;
    const int tile = blockIdx.x;
    const int tid  = threadIdx.x;

    __shared__ float hs[32][64];
    for (int x = tid; x < 32 * 64; x += 256)
        hs[x >> 6][x & 63] = hid[(size_t)tile * 2048 + x];
    __syncthreads();

    const int a0 = tid, a1 = tid + 256;
    float acc0[32], acc1[32];
    const float bv0 = bb[a0], bv1 = bb[a1];
#pragma unroll
    for (int r = 0; r < 32; ++r) { acc0[r] = bv0; acc1[r] = bv1; }

    for (int c = 0; c < 64; c += 4) {
        const float4 w0 = *(const float4*)&w[a0 * 64 + c];
        const float4 w1 = *(const float4*)&w[a1 * 64 + c];
#pragma unroll
        for (int r = 0; r < 32; ++r) {
            const float4 h4 = *(const float4*)&hs[r][c];
            acc0[r] += h4.x * w0.x + h4.y * w0.y + h4.z * w0.z + h4.w * w0.w;
            acc1[r] += h4.x * w1.x + h4.y * w1.y + h4.z * w1.z + h4.w * w1.w;
        }
    }

    const int n0 = a0 >> 6, d0 = a0 & 63;
    const int n1 = a1 >> 6, d1 = a1 & 63;
#pragma unroll
    for (int r = 0; r < 32; ++r) {
        const int bs = tile * 32 + r;
        const int b = bs >> 10, s = bs & 1023;
        outp[(((size_t)b * 8 + n0) * 1024 + s) * 64 + d0] = f2bf(acc0[r] * scl);
        outp[(((size_t)b * 8 + n1) * 1024 + s) * 64 + d1] = f2bf(acc1[r] * scl);
    }
}

// ---------------------------------------------------------------------------
// Kernel 2: positional tables (pre-scaled by log2(e)).
// posRow[n][j][l], posCol[n][i][k]
// ---------------------------------------------------------------------------
__global__ __launch_bounds__(256) void pos_kernel(
    const float* __restrict__ row_emb, const float* __restrict__ col_emb,
    const float* __restrict__ w_row,   const float* __restrict__ w_col,
    float* __restrict__ posRow, float* __restrict__ posCol)
{
    const int idx = blockIdx.x * 256 + threadIdx.x;   // 0..16383
    const int which = idx >> 13;
    const int r = idx & 8191;
    const int n = r >> 10;
    const int j = (r >> 5) & 31;
    const int l = r & 31;
    const float* emb = which ? col_emb : row_emb;
    const float* wgt = which ? w_col : w_row;
    const int e = l - j + 31;
    float acc = 0.f;
    for (int p = 0; p < 64; p += 4) {
        const float4 ev = *(const float4*)&emb[e * 64 + p];
        const float4 wv = *(const float4*)&wgt[n * 64 + p];
        acc += ev.x * wv.x + ev.y * wv.y + ev.z * wv.z + ev.w * wv.w;
    }
    (which ? posCol : posRow)[r] = acc * INVLN2;
}

// ---------------------------------------------------------------------------
// Kernel 3: V transpose -> bf16.  VtB[b][d][k] = hid[b][k][d]
// grid (16, 8): x = key-tile of 64, y = b.
// ---------------------------------------------------------------------------
__global__ __launch_bounds__(256) void vt_prep(
    const float* __restrict__ hid, short* __restrict__ VtB)
{
    const int kt = blockIdx.x;
    const int b  = blockIdx.y;
    const int tid = threadIdx.x;
    __shared__ float T[64][65];
    for (int x = tid; x < 4096; x += 256) {
        const int r = x >> 6, c = x & 63;
        T[r][c] = hid[((size_t)b * 1024 + kt * 64 + r) * 64 + c];
    }
    __syncthreads();
    const int c  = tid >> 2;          // output row (d)
    const int r0 = (tid & 3) * 16;    // key offset
    short* dst = VtB + ((size_t)b * 64 + c) * 1024 + kt * 64 + r0;
#pragma unroll
    for (int rr = 0; rr < 16; ++rr) dst[rr] = f2bf(T[r0 + rr][c]);
}

// ---------------------------------------------------------------------------
// Kernel 4: MFMA flash attention, barrier-free, no LDS.
// grid (64, 8, 8) = (16-query tile, head, batch); block = 64 (one wave).
// Swapped QK^T: D[key][q], q = lane&15.  PV computes O^T = V^T * P^T so the
// accumulator columns are also q = lane&15 (softmax state fully lane-local).
// ---------------------------------------------------------------------------
__global__ __launch_bounds__(64, 2) void attn_mfma(
    const short* __restrict__ Qb, const short* __restrict__ Kb,
    const short* __restrict__ VtB,
    const float* __restrict__ posRow, const float* __restrict__ posCol,
    float* __restrict__ headOut)
{
    const int qt = blockIdx.x;          // 0..63
    const int n  = blockIdx.y;
    const int b  = blockIdx.z;
    const int lane = threadIdx.x;
    const int g  = lane >> 4;           // 0..3
    const int qi = lane & 15;
    const int q  = qt * 16 + qi;        // global query (s index)

    // Q fragments (B operand): lane holds Q[q][32*ks + 8g .. +7]
    const short* Qrow = Qb + (((size_t)(b * 8 + n)) * 1024 + q) * 64;
    const bf16x8 qf0 = *(const bf16x8*)(Qrow + 8 * g);
    const bf16x8 qf1 = *(const bf16x8*)(Qrow + 32 + 8 * g);

    // posRow constants: key&31 = 16*(ct&1)+4g+r is kt-invariant
    const int jq = q & 31;
    const float* prows = posRow + (n * 32 + jq) * 32;
    float prow[2][4];
#pragma unroll
    for (int c2 = 0; c2 < 2; ++c2)
#pragma unroll
        for (int r = 0; r < 4; ++r)
            prow[c2][r] = prows[16 * c2 + 4 * g + r];
    const float* pcp = posCol + (n * 32 + (qt >> 1)) * 32;

    const short* Kbase = Kb + (((size_t)(b * 8 + n)) * 1024) * 64;
    const short* Vbase = VtB + ((size_t)b * 64) * 1024;

    float m = -1e30f, lsum = 0.f;
    f32x4 oacc[4];
#pragma unroll
    for (int dt = 0; dt < 4; ++dt) oacc[dt] = (f32x4){0.f, 0.f, 0.f, 0.f};

#pragma unroll 1
    for (int kt = 0; kt < 16; ++kt) {
        const int kb = kt * 64;

        // K fragments (A operand): lane holds K[kb+16ct+qi][32*ks + 8g .. +7]
        bf16x8 kf[4][2];
#pragma unroll
        for (int ct = 0; ct < 4; ++ct) {
            const short* kr = Kbase + ((size_t)(kb + 16 * ct + qi)) * 64;
            kf[ct][0] = *(const bf16x8*)(kr + 8 * g);
            kf[ct][1] = *(const bf16x8*)(kr + 32 + 8 * g);
        }
        // V fragments (A operand of PV): lane holds Vt[16dt+qi][kb+16ct+4g .. +3]
        bf16x4 vf[4][4];
#pragma unroll
        for (int dt = 0; dt < 4; ++dt) {
            const short* vr = Vbase + ((size_t)(16 * dt + qi)) * 1024 + kb + 4 * g;
#pragma unroll
            for (int ct = 0; ct < 4; ++ct)
                vf[ct][dt] = *(const bf16x4*)(vr + 16 * ct);
        }
        const float pc0 = pcp[2 * kt];
        const float pc1 = pcp[2 * kt + 1];

        // scores: D[key][q], key = kb + 16ct + 4g + r, q = qt*16 + (lane&15)
        f32x4 sc[4];
#pragma unroll
        for (int ct = 0; ct < 4; ++ct) {
            f32x4 c = (f32x4){0.f, 0.f, 0.f, 0.f};
            c = __builtin_amdgcn_mfma_f32_16x16x32_bf16(kf[ct][0], qf0, c, 0, 0, 0);
            c = __builtin_amdgcn_mfma_f32_16x16x32_bf16(kf[ct][1], qf1, c, 0, 0, 0);
            sc[ct] = c;
        }
#pragma unroll
        for (int ct = 0; ct < 4; ++ct) {
            const float pc = (ct < 2) ? pc0 : pc1;
#pragma unroll
            for (int r = 0; r < 4; ++r)
                sc[ct][r] += prow[ct & 1][r] + pc;
        }

        // online softmax over this tile's 64 keys (exp2 domain)
        float tmax = sc[0][0];
#pragma unroll
        for (int ct = 0; ct < 4; ++ct)
#pragma unroll
            for (int r = 0; r < 4; ++r) tmax = fmaxf(tmax, sc[ct][r]);
        tmax = fmaxf(tmax, __shfl_xor(tmax, 16));
        tmax = fmaxf(tmax, __shfl_xor(tmax, 32));
        const float mnew = fmaxf(m, tmax);
        const float alpha = __builtin_amdgcn_exp2f(m - mnew);
        float p[4][4];
        float psum = 0.f;
#pragma unroll
        for (int ct = 0; ct < 4; ++ct)
#pragma unroll
            for (int r = 0; r < 4; ++r) {
                p[ct][r] = __builtin_amdgcn_exp2f(sc[ct][r] - mnew);
                psum += p[ct][r];
            }
        psum += __shfl_xor(psum, 16);
        psum += __shfl_xor(psum, 32);
        lsum = lsum * alpha + psum;
        m = mnew;
#pragma unroll
        for (int dt = 0; dt < 4; ++dt) oacc[dt] *= alpha;

        // P fragments (B operand): element i = P[q][kb+16ct+4g+i] = p[ct][i]
        bf16x4 pf[4];
#pragma unroll
        for (int ct = 0; ct < 4; ++ct) {
            bf16x4 t;
            t[0] = f2bf(p[ct][0]); t[1] = f2bf(p[ct][1]);
            t[2] = f2bf(p[ct][2]); t[3] = f2bf(p[ct][3]);
            pf[ct] = t;
        }
        // PV: O^T[d][q] += Vt[d][k] * P^T[k][q]
#pragma unroll
        for (int dt = 0; dt < 4; ++dt)
#pragma unroll
            for (int ct = 0; ct < 4; ++ct)
                oacc[dt] = MFMA16(vf[ct][dt], pf[ct], oacc[dt]);
    }

    // epilogue: O^T element (d = 16dt+4g+r, q) -> headOut[b][q][n][d]
    const float inv = 1.0f / lsum;
    float* orow = headOut + (((size_t)b * 1024 + q) * 8 + n) * 64;
#pragma unroll
    for (int dt = 0; dt < 4; ++dt)
#pragma unroll
        for (int r = 0; r < 4; ++r)
            orow[16 * dt + 4 * g + r] = oacc[dt][r] * inv;
}

// ---------------------------------------------------------------------------
// Kernel 5: final projection  out[row][d] = b_v[d] + sum_a ho[row][a]*w_v[d][a]
// ---------------------------------------------------------------------------
__global__ __launch_bounds__(256) void v_proj(
    const float* __restrict__ ho, const float* __restrict__ wv,
    const float* __restrict__ bv, float* __restrict__ out)
{
    const int tid = threadIdx.x;
    __shared__ float hs[4][512];
    for (int x = tid; x < 2048; x += 256)
        hs[x >> 9][x & 511] = ho[(size_t)blockIdx.x * 2048 + x];
    __syncthreads();

    const int w = tid >> 6;
    const int d = tid & 63;
    const int row = blockIdx.x * 4 + w;

    float acc = bv[d];
    const float4* wv4 = (const float4*)(wv + (size_t)d * 512);
    const float4* hs4 = (const float4*)hs[w];
#pragma unroll 8
    for (int a4 = 0; a4 < 128; ++a4) {
        const float4 wr = wv4[a4];
        const float4 hr = hs4[a4];
        acc += hr.x * wr.x + hr.y * wr.y + hr.z * wr.z + hr.w * wr.w;
    }
    out[(size_t)row * 64 + d] = acc;
}

// ---------------------------------------------------------------------------
extern "C" void kernel_launch(void* const* d_in, const int* in_sizes, int n_in,
                              void* d_out, int out_size, void* d_ws, size_t ws_size,
                              hipStream_t stream)
{
    const float* hid     = (const float*)d_in[0];
    const float* row_emb = (const float*)d_in[2];
    const float* col_emb = (const float*)d_in[3];
    const float* w_row   = (const float*)d_in[4];
    const float* w_col   = (const float*)d_in[5];
    const float* w_q     = (const float*)d_in[6];
    const float* b_q     = (const float*)d_in[7];
    const float* w_k     = (const float*)d_in[8];
    const float* b_k     = (const float*)d_in[9];
    const float* w_v     = (const float*)d_in[10];
    const float* b_v     = (const float*)d_in[11];
    float* out = (float*)d_out;

    // ws: Q bf16 8MB | K bf16 8MB | VtB bf16 1MB | posRow 32KB | posCol 32KB | headOut f32 16MB
    short* Qw     = (short*)d_ws;
    short* Kw     = Qw + (size_t)SB * SNH * SS * SC;
    short* VtB    = Kw + (size_t)SB * SNH * SS * SC;
    float* posRow = (float*)(VtB + (size_t)SB * SC * SS);
    float* posCol = posRow + SNH * 32 * 32;
    float* headOut = posCol + SNH * 32 * 32;

    qk_proj<<<dim3(256, 2), 256, 0, stream>>>(hid, w_q, b_q, w_k, b_k, Qw, Kw);
    pos_kernel<<<64, 256, 0, stream>>>(row_emb, col_emb, w_row, w_col, posRow, posCol);
    vt_prep<<<dim3(16, 8), 256, 0, stream>>>(hid, VtB);
    attn_mfma<<<dim3(64, 8, 8), 64, 0, stream>>>(Qw, Kw, VtB, posRow, posCol, headOut);
    v_proj<<<2048, 256, 0, stream>>>(headOut, w_v, b_v, out);
}

// Round 3
// 197.666 us; speedup vs baseline: 3.1511x; 1.6586x over previous
//
#include <hip/hip_runtime.h>
#include <hip/hip_bf16.h>
#include <cstdint>
#include <cstddef>

// B=8, W=32, H=32, C=64, NH=8, P=64, M=32, AH=512, S=W*H=1024
#define SB 8
#define SNH 8
#define SS 1024
#define SC 64

typedef __attribute__((ext_vector_type(8))) short bf16x8;
typedef __attribute__((ext_vector_type(4))) short bf16x4;
typedef __attribute__((ext_vector_type(4))) float f32x4;

#define INVLN2 1.44269504088896f
#define QSCALE (0.125f * INVLN2)

static __device__ __forceinline__ short f2bf(float f) {
    unsigned u = __builtin_bit_cast(unsigned, f);
    u = (u + 0x7fffu + ((u >> 16) & 1u)) >> 16;   // RNE
    return (short)u;
}

#if __has_builtin(__builtin_amdgcn_mfma_f32_16x16x16bf16_1k)
#define MFMA16(a, b, c) __builtin_amdgcn_mfma_f32_16x16x16bf16_1k((a), (b), (c), 0, 0, 0)
#else
static __device__ __forceinline__ f32x4 mfma16_asm(bf16x4 a, bf16x4 b, f32x4 c) {
    asm volatile("v_mfma_f32_16x16x16_bf16 %0, %1, %2, %0\n\ts_nop 7\n\ts_nop 7"
                 : "+v"(c) : "v"(a), "v"(b));
    return c;
}
#define MFMA16(a, b, c) mfma16_asm((a), (b), (c))
#endif

// ---------------------------------------------------------------------------
// Kernel 1: Q/K projection -> bf16.  Q pre-scaled by 0.125*log2(e).
// ---------------------------------------------------------------------------
__global__ __launch_bounds__(256) void qk_proj(
    const float* __restrict__ hid,
    const float* __restrict__ wq, const float* __restrict__ bq,
    const float* __restrict__ wk, const float* __restrict__ bk,
    short* __restrict__ Qw, short* __restrict__ Kw)
{
    const float* w  = blockIdx.y ? wk : wq;
    const float* bb = blockIdx.y ? bk : bq;
    short* outp     = blockIdx.y ? Kw : Qw;
    const float scl = blockIdx.y ? 1.0f : QSCALE;
    const int tile = blockIdx.x;
    const int tid  = threadIdx.x;

    __shared__ float hs[32][64];
    for (int x = tid; x < 32 * 64; x += 256)
        hs[x >> 6][x & 63] = hid[(size_t)tile * 2048 + x];
    __syncthreads();

    const int a0 = tid, a1 = tid + 256;
    float acc0[32], acc1[32];
    const float bv0 = bb[a0], bv1 = bb[a1];
#pragma unroll
    for (int r = 0; r < 32; ++r) { acc0[r] = bv0; acc1[r] = bv1; }

    for (int c = 0; c < 64; c += 4) {
        const float4 w0 = *(const float4*)&w[a0 * 64 + c];
        const float4 w1 = *(const float4*)&w[a1 * 64 + c];
#pragma unroll
        for (int r = 0; r < 32; ++r) {
            const float4 h4 = *(const float4*)&hs[r][c];
            acc0[r] += h4.x * w0.x + h4.y * w0.y + h4.z * w0.z + h4.w * w0.w;
            acc1[r] += h4.x * w1.x + h4.y * w1.y + h4.z * w1.z + h4.w * w1.w;
        }
    }

    const int n0 = a0 >> 6, d0 = a0 & 63;
    const int n1 = a1 >> 6, d1 = a1 & 63;
#pragma unroll
    for (int r = 0; r < 32; ++r) {
        const int bs = tile * 32 + r;
        const int b = bs >> 10, s = bs & 1023;
        outp[(((size_t)b * 8 + n0) * 1024 + s) * 64 + d0] = f2bf(acc0[r] * scl);
        outp[(((size_t)b * 8 + n1) * 1024 + s) * 64 + d1] = f2bf(acc1[r] * scl);
    }
}

// ---------------------------------------------------------------------------
// Kernel 2: positional tables (pre-scaled by log2(e)).
// ---------------------------------------------------------------------------
__global__ __launch_bounds__(256) void pos_kernel(
    const float* __restrict__ row_emb, const float* __restrict__ col_emb,
    const float* __restrict__ w_row,   const float* __restrict__ w_col,
    float* __restrict__ posRow, float* __restrict__ posCol)
{
    const int idx = blockIdx.x * 256 + threadIdx.x;   // 0..16383
    const int which = idx >> 13;
    const int r = idx & 8191;
    const int n = r >> 10;
    const int j = (r >> 5) & 31;
    const int l = r & 31;
    const float* emb = which ? col_emb : row_emb;
    const float* wgt = which ? w_col : w_row;
    const int e = l - j + 31;
    float acc = 0.f;
    for (int p = 0; p < 64; p += 4) {
        const float4 ev = *(const float4*)&emb[e * 64 + p];
        const float4 wv = *(const float4*)&wgt[n * 64 + p];
        acc += ev.x * wv.x + ev.y * wv.y + ev.z * wv.z + ev.w * wv.w;
    }
    (which ? posCol : posRow)[r] = acc * INVLN2;
}

// ---------------------------------------------------------------------------
// Kernel 3: V transpose -> bf16.  VtB[b][d][k] = hid[b][k][d]
// ---------------------------------------------------------------------------
__global__ __launch_bounds__(256) void vt_prep(
    const float* __restrict__ hid, short* __restrict__ VtB)
{
    const int kt = blockIdx.x;
    const int b  = blockIdx.y;
    const int tid = threadIdx.x;
    __shared__ float T[64][65];
    for (int x = tid; x < 4096; x += 256) {
        const int r = x >> 6, c = x & 63;
        T[r][c] = hid[((size_t)b * 1024 + kt * 64 + r) * 64 + c];
    }
    __syncthreads();
    const int c  = tid >> 2;
    const int r0 = (tid & 3) * 16;
    short* dst = VtB + ((size_t)b * 64 + c) * 1024 + kt * 64 + r0;
#pragma unroll
    for (int rr = 0; rr < 16; ++rr) dst[rr] = f2bf(T[r0 + rr][c]);
}

// ---------------------------------------------------------------------------
// Kernel 4: MFMA flash attention, LDS-staged K/V, double-buffered, swizzled.
// grid (8, 8, 8) = (128-query block, head, batch); 256 threads = 4 waves.
// Wave w handles q-tiles qt0 = qblk*8 + 2w and qt0+1 (32 queries).
// K/V 64-key tile staged to LDS per block (reg-staged, XOR-swizzled chunks).
// Swapped QK^T (q = lane&15 lane-local softmax), PV via O^T = V^T P^T.
// ---------------------------------------------------------------------------
__global__ __launch_bounds__(256, 2) void attn_mfma(
    const short* __restrict__ Qb, const short* __restrict__ Kb,
    const short* __restrict__ VtB,
    const float* __restrict__ posRow, const float* __restrict__ posCol,
    float* __restrict__ headOut)
{
    const int qblk = blockIdx.x;        // 0..7
    const int n  = blockIdx.y;
    const int b  = blockIdx.z;
    const int tid  = threadIdx.x;
    const int w    = tid >> 6;
    const int lane = tid & 63;
    const int g  = lane >> 4;           // 0..3
    const int qi = lane & 15;
    const int qt0 = qblk * 8 + w * 2;   // even
    const int swz = qi & 7;

    __shared__ __align__(16) short Kt[2][4096];   // [buf][row*64 + col], 16B-chunk swizzled
    __shared__ __align__(16) short Vt[2][4096];

    // Q fragments (B operand) + posRow constants for both q-tiles
    bf16x8 qf[2][2];
    float prow[2][2][4];
#pragma unroll
    for (int t = 0; t < 2; ++t) {
        const int q = (qt0 + t) * 16 + qi;
        const short* Qrow = Qb + (((size_t)(b * 8 + n)) * 1024 + q) * 64;
        qf[t][0] = *(const bf16x8*)(Qrow + 8 * g);
        qf[t][1] = *(const bf16x8*)(Qrow + 32 + 8 * g);
        const float* prows = posRow + (n * 32 + (q & 31)) * 32;
#pragma unroll
        for (int c2 = 0; c2 < 2; ++c2)
#pragma unroll
            for (int r = 0; r < 4; ++r)
                prow[t][c2][r] = prows[16 * c2 + 4 * g + r];
    }
    // both q-tiles share the same i = qt0>>1
    const float* pcp = posCol + (n * 32 + (qt0 >> 1)) * 32;

    const short* Kbase = Kb + (((size_t)(b * 8 + n)) * 1024) * 64;
    const short* Vbase = VtB + ((size_t)b * 64) * 1024;

    // staging geometry: thread handles 16B chunks (srow, c16) and (srow+32, c16)
    const int c16 = tid & 7;
    const int srow = tid >> 3;          // 0..31
    const int woffA = srow * 128 + ((c16 ^ (srow & 7)) << 4);
    const int woffB = (srow + 32) * 128 + ((c16 ^ (srow & 7)) << 4);
    const short* kp0 = Kbase + (size_t)srow * 64 + c16 * 8;
    const short* kp1 = Kbase + (size_t)(srow + 32) * 64 + c16 * 8;
    const short* vp0 = Vbase + (size_t)srow * 1024 + c16 * 8;
    const short* vp1 = Vbase + (size_t)(srow + 32) * 1024 + c16 * 8;

    // prologue: stage tile 0 into buffer 0
    {
        const float4 ka  = *(const float4*)kp0;
        const float4 kb4 = *(const float4*)kp1;
        const float4 va  = *(const float4*)vp0;
        const float4 vb4 = *(const float4*)vp1;
        *(float4*)((char*)&Kt[0][0] + woffA) = ka;
        *(float4*)((char*)&Kt[0][0] + woffB) = kb4;
        *(float4*)((char*)&Vt[0][0] + woffA) = va;
        *(float4*)((char*)&Vt[0][0] + woffB) = vb4;
    }
    __syncthreads();

    float m[2] = {-1e30f, -1e30f}, lsum[2] = {0.f, 0.f};
    f32x4 oacc[2][4];
#pragma unroll
    for (int t = 0; t < 2; ++t)
#pragma unroll
        for (int dt = 0; dt < 4; ++dt) oacc[t][dt] = (f32x4){0.f, 0.f, 0.f, 0.f};

    int cur = 0;
#pragma unroll 1
    for (int kt = 0; kt < 16; ++kt) {
        // issue next tile's global loads early (latency hides under compute)
        float4 ka, kb4, va, vb4;
        if (kt < 15) {
            const size_t ko = (size_t)(kt + 1) * 4096;   // (kb)*64 shorts
            const int vo = (kt + 1) * 64;
            ka  = *(const float4*)(kp0 + ko);
            kb4 = *(const float4*)(kp1 + ko);
            va  = *(const float4*)(vp0 + vo);
            vb4 = *(const float4*)(vp1 + vo);
        }

        const char* Ktc = (const char*)&Kt[cur][0];
        const char* Vtc = (const char*)&Vt[cur][0];

        // K fragments (A operand): row 16ct+qi, chunks g and 4+g (swizzled)
        bf16x8 kf[4][2];
#pragma unroll
        for (int ct = 0; ct < 4; ++ct) {
            const int rb = (16 * ct + qi) * 128;
            kf[ct][0] = *(const bf16x8*)(Ktc + rb + (((g    ) ^ swz) << 4));
            kf[ct][1] = *(const bf16x8*)(Ktc + rb + (((g + 4) ^ swz) << 4));
        }

        // QK^T: sc[t][ct][r] = S[key = kt*64+16ct+4g+r][q]
        __builtin_amdgcn_s_setprio(1);
        f32x4 sc[2][4];
#pragma unroll
        for (int t = 0; t < 2; ++t)
#pragma unroll
            for (int ct = 0; ct < 4; ++ct) {
                f32x4 c = (f32x4){0.f, 0.f, 0.f, 0.f};
                c = __builtin_amdgcn_mfma_f32_16x16x32_bf16(kf[ct][0], qf[t][0], c, 0, 0, 0);
                c = __builtin_amdgcn_mfma_f32_16x16x32_bf16(kf[ct][1], qf[t][1], c, 0, 0, 0);
                sc[t][ct] = c;
            }
        __builtin_amdgcn_s_setprio(0);

        // V fragments (A operand of PV): row 16dt+qi, 8B at chunk 2ct+(g>>1), half g&1
        bf16x4 vf[4][4];
#pragma unroll
        for (int dt = 0; dt < 4; ++dt) {
            const int rb = (16 * dt + qi) * 128;
#pragma unroll
            for (int ct = 0; ct < 4; ++ct)
                vf[ct][dt] = *(const bf16x4*)(Vtc + rb +
                                (((2 * ct + (g >> 1)) ^ swz) << 4) + ((g & 1) * 8));
        }

        const float pc0 = pcp[2 * kt];
        const float pc1 = pcp[2 * kt + 1];

        // pos add + online softmax (exp2 domain), both q-tiles
        bf16x4 pf[2][4];
#pragma unroll
        for (int t = 0; t < 2; ++t) {
#pragma unroll
            for (int ct = 0; ct < 4; ++ct) {
                const float pc = (ct < 2) ? pc0 : pc1;
#pragma unroll
                for (int r = 0; r < 4; ++r)
                    sc[t][ct][r] += prow[t][ct & 1][r] + pc;
            }
            float tmax = fmaxf(fmaxf(sc[t][0][0], sc[t][0][1]), fmaxf(sc[t][0][2], sc[t][0][3]));
#pragma unroll
            for (int ct = 1; ct < 4; ++ct) {
                const float a = fmaxf(fmaxf(sc[t][ct][0], sc[t][ct][1]),
                                      fmaxf(sc[t][ct][2], sc[t][ct][3]));
                tmax = fmaxf(tmax, a);
            }
            tmax = fmaxf(tmax, __shfl_xor(tmax, 16));
            tmax = fmaxf(tmax, __shfl_xor(tmax, 32));
            const float mnew = fmaxf(m[t], tmax);
            const float alpha = __builtin_amdgcn_exp2f(m[t] - mnew);
            float psum = 0.f;
            float p[4][4];
#pragma unroll
            for (int ct = 0; ct < 4; ++ct)
#pragma unroll
                for (int r = 0; r < 4; ++r) {
                    p[ct][r] = __builtin_amdgcn_exp2f(sc[t][ct][r] - mnew);
                    psum += p[ct][r];
                }
            psum += __shfl_xor(psum, 16);
            psum += __shfl_xor(psum, 32);
            lsum[t] = lsum[t] * alpha + psum;
            m[t] = mnew;
#pragma unroll
            for (int dt = 0; dt < 4; ++dt) oacc[t][dt] *= alpha;
#pragma unroll
            for (int ct = 0; ct < 4; ++ct) {
                bf16x4 pp;
                pp[0] = f2bf(p[ct][0]); pp[1] = f2bf(p[ct][1]);
                pp[2] = f2bf(p[ct][2]); pp[3] = f2bf(p[ct][3]);
                pf[t][ct] = pp;
            }
        }

        // PV: O^T[d][q] += Vt[d][k] * P^T[k][q]
        __builtin_amdgcn_s_setprio(1);
#pragma unroll
        for (int t = 0; t < 2; ++t)
#pragma unroll
            for (int dt = 0; dt < 4; ++dt)
#pragma unroll
                for (int ct = 0; ct < 4; ++ct)
                    oacc[t][dt] = MFMA16(vf[ct][dt], pf[t][ct], oacc[t][dt]);
        __builtin_amdgcn_s_setprio(0);

        if (kt < 15) {
            char* Kn = (char*)&Kt[cur ^ 1][0];
            char* Vn = (char*)&Vt[cur ^ 1][0];
            *(float4*)(Kn + woffA) = ka;
            *(float4*)(Kn + woffB) = kb4;
            *(float4*)(Vn + woffA) = va;
            *(float4*)(Vn + woffB) = vb4;
            __syncthreads();
            cur ^= 1;
        }
    }

    // epilogue
#pragma unroll
    for (int t = 0; t < 2; ++t) {
        const float inv = 1.0f / lsum[t];
        const int q = (qt0 + t) * 16 + qi;
        float* orow = headOut + (((size_t)b * 1024 + q) * 8 + n) * 64;
#pragma unroll
        for (int dt = 0; dt < 4; ++dt) {
            *(float4*)&orow[16 * dt + 4 * g] =
                make_float4(oacc[t][dt][0] * inv, oacc[t][dt][1] * inv,
                            oacc[t][dt][2] * inv, oacc[t][dt][3] * inv);
        }
    }
}

// ---------------------------------------------------------------------------
// Kernel 5: final projection  out[row][d] = b_v[d] + sum_a ho[row][a]*w_v[d][a]
// ---------------------------------------------------------------------------
__global__ __launch_bounds__(256) void v_proj(
    const float* __restrict__ ho, const float* __restrict__ wv,
    const float* __restrict__ bv, float* __restrict__ out)
{
    const int tid = threadIdx.x;
    __shared__ float hs[4][512];
    for (int x = tid; x < 2048; x += 256)
        hs[x >> 9][x & 511] = ho[(size_t)blockIdx.x * 2048 + x];
    __syncthreads();

    const int w = tid >> 6;
    const int d = tid & 63;
    const int row = blockIdx.x * 4 + w;

    float acc = bv[d];
    const float4* wv4 = (const float4*)(wv + (size_t)d * 512);
    const float4* hs4 = (const float4*)hs[w];
#pragma unroll 8
    for (int a4 = 0; a4 < 128; ++a4) {
        const float4 wr = wv4[a4];
        const float4 hr = hs4[a4];
        acc += hr.x * wr.x + hr.y * wr.y + hr.z * wr.z + hr.w * wr.w;
    }
    out[(size_t)row * 64 + d] = acc;
}

// ---------------------------------------------------------------------------
extern "C" void kernel_launch(void* const* d_in, const int* in_sizes, int n_in,
                              void* d_out, int out_size, void* d_ws, size_t ws_size,
                              hipStream_t stream)
{
    const float* hid     = (const float*)d_in[0];
    const float* row_emb = (const float*)d_in[2];
    const float* col_emb = (const float*)d_in[3];
    const float* w_row   = (const float*)d_in[4];
    const float* w_col   = (const float*)d_in[5];
    const float* w_q     = (const float*)d_in[6];
    const float* b_q     = (const float*)d_in[7];
    const float* w_k     = (const float*)d_in[8];
    const float* b_k     = (const float*)d_in[9];
    const float* w_v     = (const float*)d_in[10];
    const float* b_v     = (const float*)d_in[11];
    float* out = (float*)d_out;

    // ws: Q bf16 8MB | K bf16 8MB | VtB bf16 1MB | posRow 32KB | posCol 32KB | headOut f32 16MB
    short* Qw     = (short*)d_ws;
    short* Kw     = Qw + (size_t)SB * SNH * SS * SC;
    short* VtB    = Kw + (size_t)SB * SNH * SS * SC;
    float* posRow = (float*)(VtB + (size_t)SB * SC * SS);
    float* posCol = posRow + SNH * 32 * 32;
    float* headOut = posCol + SNH * 32 * 32;

    qk_proj<<<dim3(256, 2), 256, 0, stream>>>(hid, w_q, b_q, w_k, b_k, Qw, Kw);
    pos_kernel<<<64, 256, 0, stream>>>(row_emb, col_emb, w_row, w_col, posRow, posCol);
    vt_prep<<<dim3(16, 8), 256, 0, stream>>>(hid, VtB);
    attn_mfma<<<dim3(8, 8, 8), 256, 0, stream>>>(Qw, Kw, VtB, posRow, posCol, headOut);
    v_proj<<<2048, 256, 0, stream>>>(headOut, w_v, b_v, out);
}

// Round 4
// 95.166 us; speedup vs baseline: 6.5450x; 2.0771x over previous
//
#include <hip/hip_runtime.h>
#include <hip/hip_bf16.h>
#include <cstdint>
#include <cstddef>

// B=8, W=32, H=32, C=64, NH=8, P=64, M=32, AH=512, S=W*H=1024
#define SB 8
#define SNH 8
#define SS 1024
#define SC 64

typedef __attribute__((ext_vector_type(8))) short bf16x8;
typedef __attribute__((ext_vector_type(4))) short bf16x4;
typedef __attribute__((ext_vector_type(4))) float f32x4;

#define INVLN2 1.44269504088896f
#define QSCALE (0.125f * INVLN2)

static __device__ __forceinline__ short f2bf(float f) {
    unsigned u = __builtin_bit_cast(unsigned, f);
    u = (u + 0x7fffu + ((u >> 16) & 1u)) >> 16;   // RNE
    return (short)u;
}

#if __has_builtin(__builtin_amdgcn_mfma_f32_16x16x16bf16_1k)
#define MFMA16(a, b, c) __builtin_amdgcn_mfma_f32_16x16x16bf16_1k((a), (b), (c), 0, 0, 0)
#else
static __device__ __forceinline__ f32x4 mfma16_asm(bf16x4 a, bf16x4 b, f32x4 c) {
    asm volatile("v_mfma_f32_16x16x16_bf16 %0, %1, %2, %0\n\ts_nop 7\n\ts_nop 7"
                 : "+v"(c) : "v"(a), "v"(b));
    return c;
}
#define MFMA16(a, b, c) mfma16_asm((a), (b), (c))
#endif

// ---------------------------------------------------------------------------
// Kernel 1: Q/K projection -> bf16.  Q pre-scaled by 0.125*log2(e).
// ---------------------------------------------------------------------------
__global__ __launch_bounds__(256) void qk_proj(
    const float* __restrict__ hid,
    const float* __restrict__ wq, const float* __restrict__ bq,
    const float* __restrict__ wk, const float* __restrict__ bk,
    short* __restrict__ Qw, short* __restrict__ Kw)
{
    const float* w  = blockIdx.y ? wk : wq;
    const float* bb = blockIdx.y ? bk : bq;
    short* outp     = blockIdx.y ? Kw : Qw;
    const float scl = blockIdx.y ? 1.0f : QSCALE;
    const int tile = blockIdx.x;
    const int tid  = threadIdx.x;

    __shared__ float hs[32][64];
    for (int x = tid; x < 32 * 64; x += 256)
        hs[x >> 6][x & 63] = hid[(size_t)tile * 2048 + x];
    __syncthreads();

    const int a0 = tid, a1 = tid + 256;
    float acc0[32], acc1[32];
    const float bv0 = bb[a0], bv1 = bb[a1];
#pragma unroll
    for (int r = 0; r < 32; ++r) { acc0[r] = bv0; acc1[r] = bv1; }

    for (int c = 0; c < 64; c += 4) {
        const float4 w0 = *(const float4*)&w[a0 * 64 + c];
        const float4 w1 = *(const float4*)&w[a1 * 64 + c];
#pragma unroll
        for (int r = 0; r < 32; ++r) {
            const float4 h4 = *(const float4*)&hs[r][c];
            acc0[r] += h4.x * w0.x + h4.y * w0.y + h4.z * w0.z + h4.w * w0.w;
            acc1[r] += h4.x * w1.x + h4.y * w1.y + h4.z * w1.z + h4.w * w1.w;
        }
    }

    const int n0 = a0 >> 6, d0 = a0 & 63;
    const int n1 = a1 >> 6, d1 = a1 & 63;
#pragma unroll
    for (int r = 0; r < 32; ++r) {
        const int bs = tile * 32 + r;
        const int b = bs >> 10, s = bs & 1023;
        outp[(((size_t)b * 8 + n0) * 1024 + s) * 64 + d0] = f2bf(acc0[r] * scl);
        outp[(((size_t)b * 8 + n1) * 1024 + s) * 64 + d1] = f2bf(acc1[r] * scl);
    }
}

// ---------------------------------------------------------------------------
// Kernel 2: positional tables (pre-scaled by log2(e)) + wv -> bf16 convert.
// blocks 0..63: pos tables; blocks 64..79: wvB conversion.
// ---------------------------------------------------------------------------
__global__ __launch_bounds__(256) void pos_kernel(
    const float* __restrict__ row_emb, const float* __restrict__ col_emb,
    const float* __restrict__ w_row,   const float* __restrict__ w_col,
    const float* __restrict__ wv,      short* __restrict__ wvB,
    float* __restrict__ posRow, float* __restrict__ posCol)
{
    if (blockIdx.x >= 64) {
        const int t = (blockIdx.x - 64) * 256 + threadIdx.x;   // 0..4095
        const float4 a = *(const float4*)&wv[t * 8];
        const float4 b = *(const float4*)&wv[t * 8 + 4];
        bf16x8 o;
        o[0] = f2bf(a.x); o[1] = f2bf(a.y); o[2] = f2bf(a.z); o[3] = f2bf(a.w);
        o[4] = f2bf(b.x); o[5] = f2bf(b.y); o[6] = f2bf(b.z); o[7] = f2bf(b.w);
        *(bf16x8*)&wvB[t * 8] = o;
        return;
    }
    const int idx = blockIdx.x * 256 + threadIdx.x;   // 0..16383
    const int which = idx >> 13;
    const int r = idx & 8191;
    const int n = r >> 10;
    const int j = (r >> 5) & 31;
    const int l = r & 31;
    const float* emb = which ? col_emb : row_emb;
    const float* wgt = which ? w_col : w_row;
    const int e = l - j + 31;
    float acc = 0.f;
    for (int p = 0; p < 64; p += 4) {
        const float4 ev = *(const float4*)&emb[e * 64 + p];
        const float4 wv4 = *(const float4*)&wgt[n * 64 + p];
        acc += ev.x * wv4.x + ev.y * wv4.y + ev.z * wv4.z + ev.w * wv4.w;
    }
    (which ? posCol : posRow)[r] = acc * INVLN2;
}

// ---------------------------------------------------------------------------
// Kernel 3: V transpose -> bf16.  VtB[b][d][k] = hid[b][k][d]
// ---------------------------------------------------------------------------
__global__ __launch_bounds__(256) void vt_prep(
    const float* __restrict__ hid, short* __restrict__ VtB)
{
    const int kt = blockIdx.x;
    const int b  = blockIdx.y;
    const int tid = threadIdx.x;
    __shared__ float T[64][65];
    for (int x = tid; x < 4096; x += 256) {
        const int r = x >> 6, c = x & 63;
        T[r][c] = hid[((size_t)b * 1024 + kt * 64 + r) * 64 + c];
    }
    __syncthreads();
    const int c  = tid >> 2;
    const int r0 = (tid & 3) * 16;
    short* dst = VtB + ((size_t)b * 64 + c) * 1024 + kt * 64 + r0;
#pragma unroll
    for (int rr = 0; rr < 16; ++rr) dst[rr] = f2bf(T[r0 + rr][c]);
}

// ---------------------------------------------------------------------------
// Kernel 4: MFMA flash attention, LDS-staged K/V, double-buffered, swizzled.
// grid (8, 8, 8) = (128-query block, head, batch); 256 threads = 4 waves.
// Epilogue writes bf16 headOut [b][s][a = n*64+d].
// ---------------------------------------------------------------------------
__global__ __launch_bounds__(256, 2) void attn_mfma(
    const short* __restrict__ Qb, const short* __restrict__ Kb,
    const short* __restrict__ VtB,
    const float* __restrict__ posRow, const float* __restrict__ posCol,
    short* __restrict__ hoB)
{
    const int qblk = blockIdx.x;        // 0..7
    const int n  = blockIdx.y;
    const int b  = blockIdx.z;
    const int tid  = threadIdx.x;
    const int w    = tid >> 6;
    const int lane = tid & 63;
    const int g  = lane >> 4;           // 0..3
    const int qi = lane & 15;
    const int qt0 = qblk * 8 + w * 2;   // even
    const int swz = qi & 7;

    __shared__ __align__(16) short Kt[2][4096];   // [buf][row*64 + col], 16B-chunk swizzled
    __shared__ __align__(16) short Vt[2][4096];

    // Q fragments (B operand) + posRow constants for both q-tiles
    bf16x8 qf[2][2];
    float prow[2][2][4];
#pragma unroll
    for (int t = 0; t < 2; ++t) {
        const int q = (qt0 + t) * 16 + qi;
        const short* Qrow = Qb + (((size_t)(b * 8 + n)) * 1024 + q) * 64;
        qf[t][0] = *(const bf16x8*)(Qrow + 8 * g);
        qf[t][1] = *(const bf16x8*)(Qrow + 32 + 8 * g);
        const float* prows = posRow + (n * 32 + (q & 31)) * 32;
#pragma unroll
        for (int c2 = 0; c2 < 2; ++c2)
#pragma unroll
            for (int r = 0; r < 4; ++r)
                prow[t][c2][r] = prows[16 * c2 + 4 * g + r];
    }
    const float* pcp = posCol + (n * 32 + (qt0 >> 1)) * 32;

    const short* Kbase = Kb + (((size_t)(b * 8 + n)) * 1024) * 64;
    const short* Vbase = VtB + ((size_t)b * 64) * 1024;

    // staging geometry: thread handles 16B chunks (srow, c16) and (srow+32, c16)
    const int c16 = tid & 7;
    const int srow = tid >> 3;          // 0..31
    const int woffA = srow * 128 + ((c16 ^ (srow & 7)) << 4);
    const int woffB = (srow + 32) * 128 + ((c16 ^ (srow & 7)) << 4);
    const short* kp0 = Kbase + (size_t)srow * 64 + c16 * 8;
    const short* kp1 = Kbase + (size_t)(srow + 32) * 64 + c16 * 8;
    const short* vp0 = Vbase + (size_t)srow * 1024 + c16 * 8;
    const short* vp1 = Vbase + (size_t)(srow + 32) * 1024 + c16 * 8;

    // prologue: stage tile 0 into buffer 0
    {
        const float4 ka  = *(const float4*)kp0;
        const float4 kb4 = *(const float4*)kp1;
        const float4 va  = *(const float4*)vp0;
        const float4 vb4 = *(const float4*)vp1;
        *(float4*)((char*)&Kt[0][0] + woffA) = ka;
        *(float4*)((char*)&Kt[0][0] + woffB) = kb4;
        *(float4*)((char*)&Vt[0][0] + woffA) = va;
        *(float4*)((char*)&Vt[0][0] + woffB) = vb4;
    }
    __syncthreads();

    float m[2] = {-1e30f, -1e30f}, lsum[2] = {0.f, 0.f};
    f32x4 oacc[2][4];
#pragma unroll
    for (int t = 0; t < 2; ++t)
#pragma unroll
        for (int dt = 0; dt < 4; ++dt) oacc[t][dt] = (f32x4){0.f, 0.f, 0.f, 0.f};

    int cur = 0;
#pragma unroll 1
    for (int kt = 0; kt < 16; ++kt) {
        // issue next tile's global loads early (latency hides under compute)
        float4 ka, kb4, va, vb4;
        if (kt < 15) {
            const size_t ko = (size_t)(kt + 1) * 4096;   // 64 rows * 64 shorts
            const int vo = (kt + 1) * 64;
            ka  = *(const float4*)(kp0 + ko);
            kb4 = *(const float4*)(kp1 + ko);
            va  = *(const float4*)(vp0 + vo);
            vb4 = *(const float4*)(vp1 + vo);
        }

        const char* Ktc = (const char*)&Kt[cur][0];
        const char* Vtc = (const char*)&Vt[cur][0];

        // K fragments (A operand): row 16ct+qi, chunks g and 4+g (swizzled)
        bf16x8 kf[4][2];
#pragma unroll
        for (int ct = 0; ct < 4; ++ct) {
            const int rb = (16 * ct + qi) * 128;
            kf[ct][0] = *(const bf16x8*)(Ktc + rb + (((g    ) ^ swz) << 4));
            kf[ct][1] = *(const bf16x8*)(Ktc + rb + (((g + 4) ^ swz) << 4));
        }

        // QK^T: sc[t][ct][r] = S[key = kt*64+16ct+4g+r][q]
        __builtin_amdgcn_s_setprio(1);
        f32x4 sc[2][4];
#pragma unroll
        for (int t = 0; t < 2; ++t)
#pragma unroll
            for (int ct = 0; ct < 4; ++ct) {
                f32x4 c = (f32x4){0.f, 0.f, 0.f, 0.f};
                c = __builtin_amdgcn_mfma_f32_16x16x32_bf16(kf[ct][0], qf[t][0], c, 0, 0, 0);
                c = __builtin_amdgcn_mfma_f32_16x16x32_bf16(kf[ct][1], qf[t][1], c, 0, 0, 0);
                sc[t][ct] = c;
            }
        __builtin_amdgcn_s_setprio(0);

        // V fragments (A operand of PV): row 16dt+qi, 8B at chunk 2ct+(g>>1), half g&1
        bf16x4 vf[4][4];
#pragma unroll
        for (int dt = 0; dt < 4; ++dt) {
            const int rb = (16 * dt + qi) * 128;
#pragma unroll
            for (int ct = 0; ct < 4; ++ct)
                vf[ct][dt] = *(const bf16x4*)(Vtc + rb +
                                (((2 * ct + (g >> 1)) ^ swz) << 4) + ((g & 1) * 8));
        }

        const float pc0 = pcp[2 * kt];
        const float pc1 = pcp[2 * kt + 1];

        // pos add + online softmax (exp2 domain), both q-tiles
        bf16x4 pf[2][4];
#pragma unroll
        for (int t = 0; t < 2; ++t) {
#pragma unroll
            for (int ct = 0; ct < 4; ++ct) {
                const float pc = (ct < 2) ? pc0 : pc1;
#pragma unroll
                for (int r = 0; r < 4; ++r)
                    sc[t][ct][r] += prow[t][ct & 1][r] + pc;
            }
            float tmax = fmaxf(fmaxf(sc[t][0][0], sc[t][0][1]), fmaxf(sc[t][0][2], sc[t][0][3]));
#pragma unroll
            for (int ct = 1; ct < 4; ++ct) {
                const float a = fmaxf(fmaxf(sc[t][ct][0], sc[t][ct][1]),
                                      fmaxf(sc[t][ct][2], sc[t][ct][3]));
                tmax = fmaxf(tmax, a);
            }
            tmax = fmaxf(tmax, __shfl_xor(tmax, 16));
            tmax = fmaxf(tmax, __shfl_xor(tmax, 32));
            const float mnew = fmaxf(m[t], tmax);
            const float alpha = __builtin_amdgcn_exp2f(m[t] - mnew);
            float psum = 0.f;
            float p[4][4];
#pragma unroll
            for (int ct = 0; ct < 4; ++ct)
#pragma unroll
                for (int r = 0; r < 4; ++r) {
                    p[ct][r] = __builtin_amdgcn_exp2f(sc[t][ct][r] - mnew);
                    psum += p[ct][r];
                }
            psum += __shfl_xor(psum, 16);
            psum += __shfl_xor(psum, 32);
            lsum[t] = lsum[t] * alpha + psum;
            m[t] = mnew;
#pragma unroll
            for (int dt = 0; dt < 4; ++dt) oacc[t][dt] *= alpha;
#pragma unroll
            for (int ct = 0; ct < 4; ++ct) {
                bf16x4 pp;
                pp[0] = f2bf(p[ct][0]); pp[1] = f2bf(p[ct][1]);
                pp[2] = f2bf(p[ct][2]); pp[3] = f2bf(p[ct][3]);
                pf[t][ct] = pp;
            }
        }

        // PV: O^T[d][q] += Vt[d][k] * P^T[k][q]
        __builtin_amdgcn_s_setprio(1);
#pragma unroll
        for (int t = 0; t < 2; ++t)
#pragma unroll
            for (int dt = 0; dt < 4; ++dt)
#pragma unroll
                for (int ct = 0; ct < 4; ++ct)
                    oacc[t][dt] = MFMA16(vf[ct][dt], pf[t][ct], oacc[t][dt]);
        __builtin_amdgcn_s_setprio(0);

        if (kt < 15) {
            char* Kn = (char*)&Kt[cur ^ 1][0];
            char* Vn = (char*)&Vt[cur ^ 1][0];
            *(float4*)(Kn + woffA) = ka;
            *(float4*)(Kn + woffB) = kb4;
            *(float4*)(Vn + woffA) = va;
            *(float4*)(Vn + woffB) = vb4;
            __syncthreads();
            cur ^= 1;
        }
    }

    // epilogue: bf16 headOut[b][q][n*64 + d], d = 16dt+4g+r
#pragma unroll
    for (int t = 0; t < 2; ++t) {
        const float inv = 1.0f / lsum[t];
        const int q = (qt0 + t) * 16 + qi;
        short* orow = hoB + ((size_t)(b * 1024 + q)) * 512 + n * 64;
#pragma unroll
        for (int dt = 0; dt < 4; ++dt) {
            bf16x4 ov;
            ov[0] = f2bf(oacc[t][dt][0] * inv);
            ov[1] = f2bf(oacc[t][dt][1] * inv);
            ov[2] = f2bf(oacc[t][dt][2] * inv);
            ov[3] = f2bf(oacc[t][dt][3] * inv);
            *(bf16x4*)&orow[16 * dt + 4 * g] = ov;
        }
    }
}

// ---------------------------------------------------------------------------
// Kernel 5: final projection via MFMA.
// C[8192][64] = hoB[8192][512] @ wvB^T;  out[row][d] = C + bv[d].
// grid 128 x 256: wave w owns rows blockIdx*64 + w*16.
// A-frag: lane holds hoB[row=base+qi][32ks+8g..+7]; B-frag: wvB[16ct+qi][32ks+8g..+7].
// D: row_local = 4g+r, col = qi (d = 16ct+qi).
// ---------------------------------------------------------------------------
__global__ __launch_bounds__(256) void v_proj(
    const short* __restrict__ hoB, const short* __restrict__ wvB,
    const float* __restrict__ bv, float* __restrict__ out)
{
    const int tid  = threadIdx.x;
    const int w    = tid >> 6;
    const int lane = tid & 63;
    const int g  = lane >> 4;
    const int qi = lane & 15;
    const int row0 = blockIdx.x * 64 + w * 16;

    const short* arow = hoB + (size_t)(row0 + qi) * 512 + 8 * g;

    f32x4 acc[4];
#pragma unroll
    for (int ct = 0; ct < 4; ++ct) acc[ct] = (f32x4){0.f, 0.f, 0.f, 0.f};

#pragma unroll 4
    for (int ks = 0; ks < 16; ++ks) {
        const bf16x8 af = *(const bf16x8*)(arow + ks * 32);
#pragma unroll
        for (int ct = 0; ct < 4; ++ct) {
            const bf16x8 bfr = *(const bf16x8*)(wvB + (size_t)(16 * ct + qi) * 512 + ks * 32 + 8 * g);
            acc[ct] = __builtin_amdgcn_mfma_f32_16x16x32_bf16(af, bfr, acc[ct], 0, 0, 0);
        }
    }

#pragma unroll
    for (int ct = 0; ct < 4; ++ct) {
        const float bias = bv[16 * ct + qi];
#pragma unroll
        for (int r = 0; r < 4; ++r)
            out[(size_t)(row0 + 4 * g + r) * 64 + 16 * ct + qi] = acc[ct][r] + bias;
    }
}

// ---------------------------------------------------------------------------
extern "C" void kernel_launch(void* const* d_in, const int* in_sizes, int n_in,
                              void* d_out, int out_size, void* d_ws, size_t ws_size,
                              hipStream_t stream)
{
    const float* hid     = (const float*)d_in[0];
    const float* row_emb = (const float*)d_in[2];
    const float* col_emb = (const float*)d_in[3];
    const float* w_row   = (const float*)d_in[4];
    const float* w_col   = (const float*)d_in[5];
    const float* w_q     = (const float*)d_in[6];
    const float* b_q     = (const float*)d_in[7];
    const float* w_k     = (const float*)d_in[8];
    const float* b_k     = (const float*)d_in[9];
    const float* w_v     = (const float*)d_in[10];
    const float* b_v     = (const float*)d_in[11];
    float* out = (float*)d_out;

    // ws: Q bf16 8MB | K bf16 8MB | VtB bf16 1MB | posRow 32KB | posCol 32KB | wvB 64KB | hoB bf16 8MB
    short* Qw     = (short*)d_ws;
    short* Kw     = Qw + (size_t)SB * SNH * SS * SC;
    short* VtB    = Kw + (size_t)SB * SNH * SS * SC;
    float* posRow = (float*)(VtB + (size_t)SB * SC * SS);
    float* posCol = posRow + SNH * 32 * 32;
    short* wvB    = (short*)(posCol + SNH * 32 * 32);
    short* hoB    = wvB + (size_t)SC * SNH * SC;

    qk_proj<<<dim3(256, 2), 256, 0, stream>>>(hid, w_q, b_q, w_k, b_k, Qw, Kw);
    pos_kernel<<<80, 256, 0, stream>>>(row_emb, col_emb, w_row, w_col, w_v, wvB, posRow, posCol);
    vt_prep<<<dim3(16, 8), 256, 0, stream>>>(hid, VtB);
    attn_mfma<<<dim3(8, 8, 8), 256, 0, stream>>>(Qw, Kw, VtB, posRow, posCol, hoB);
    v_proj<<<128, 256, 0, stream>>>(hoB, wvB, b_v, out);
}

// Round 5
// 75.810 us; speedup vs baseline: 8.2161x; 1.2553x over previous
//
#include <hip/hip_runtime.h>
#include <hip/hip_bf16.h>
#include <cstdint>
#include <cstddef>

// B=8, W=32, H=32, C=64, NH=8, P=64, M=32, AH=512, S=W*H=1024
#define SB 8
#define SNH 8
#define SS 1024
#define SC 64

typedef __attribute__((ext_vector_type(8))) short bf16x8;
typedef __attribute__((ext_vector_type(4))) short bf16x4;
typedef __attribute__((ext_vector_type(4))) float f32x4;

#define INVLN2 1.44269504088896f
#define QSCALE (0.125f * INVLN2)

// native RNE f32->bf16 (compiler emits v_cvt; do NOT hand-roll integer RNE)
static __device__ __forceinline__ short f2bf(float f) {
    __hip_bfloat16 h = __float2bfloat16(f);
    return __builtin_bit_cast(short, h);
}

static __device__ __forceinline__ bf16x8 cvt8(const float* __restrict__ p, float scl) {
    const float4 a = *(const float4*)p;
    const float4 b = *(const float4*)(p + 4);
    bf16x8 o;
    o[0] = f2bf(a.x * scl); o[1] = f2bf(a.y * scl); o[2] = f2bf(a.z * scl); o[3] = f2bf(a.w * scl);
    o[4] = f2bf(b.x * scl); o[5] = f2bf(b.y * scl); o[6] = f2bf(b.z * scl); o[7] = f2bf(b.w * scl);
    return o;
}

#if __has_builtin(__builtin_amdgcn_mfma_f32_16x16x16bf16_1k)
#define MFMA16(a, b, c) __builtin_amdgcn_mfma_f32_16x16x16bf16_1k((a), (b), (c), 0, 0, 0)
#else
static __device__ __forceinline__ f32x4 mfma16_asm(bf16x4 a, bf16x4 b, f32x4 c) {
    asm volatile("v_mfma_f32_16x16x16_bf16 %0, %1, %2, %0\n\ts_nop 7\n\ts_nop 7"
                 : "+v"(c) : "v"(a), "v"(b));
    return c;
}
#define MFMA16(a, b, c) mfma16_asm((a), (b), (c))
#endif

// ---------------------------------------------------------------------------
// Kernel 1: prep — pos tables, bf16 conversions (w_v, w_q*QSCALE, w_k, hid),
// and V^T (VtB[b][d][k] = hid[b][k][d], bf16).
// blocks: [0,64) pos | [64,80) wvB | [80,96) wqB | [96,112) wkB |
//         [112,368) hidB | [368,496) VtB transpose
// ---------------------------------------------------------------------------
__global__ __launch_bounds__(256) void prep(
    const float* __restrict__ row_emb, const float* __restrict__ col_emb,
    const float* __restrict__ w_row,   const float* __restrict__ w_col,
    const float* __restrict__ w_v, const float* __restrict__ w_q,
    const float* __restrict__ w_k, const float* __restrict__ hid,
    float* __restrict__ posRow, float* __restrict__ posCol,
    short* __restrict__ wvB, short* __restrict__ wqB, short* __restrict__ wkB,
    short* __restrict__ hidB, short* __restrict__ VtB)
{
    const int bx = blockIdx.x;
    const int tid = threadIdx.x;
    __shared__ float T[64][65];

    if (bx < 64) {
        const int idx = bx * 256 + tid;     // 0..16383
        const int which = idx >> 13;
        const int r = idx & 8191;
        const int n = r >> 10;
        const int j = (r >> 5) & 31;
        const int l = r & 31;
        const float* emb = which ? col_emb : row_emb;
        const float* wgt = which ? w_col : w_row;
        const int e = l - j + 31;
        float acc = 0.f;
        for (int p = 0; p < 64; p += 4) {
            const float4 ev = *(const float4*)&emb[e * 64 + p];
            const float4 wv4 = *(const float4*)&wgt[n * 64 + p];
            acc += ev.x * wv4.x + ev.y * wv4.y + ev.z * wv4.z + ev.w * wv4.w;
        }
        (which ? posCol : posRow)[r] = acc * INVLN2;
    } else if (bx < 112) {
        const int grp = (bx - 64) >> 4;     // 0=wv, 1=wq, 2=wk
        const int t = ((bx - 64) & 15) * 256 + tid;   // 0..4095
        const float* src = grp == 0 ? w_v : (grp == 1 ? w_q : w_k);
        short* dst       = grp == 0 ? wvB : (grp == 1 ? wqB : wkB);
        const float scl  = grp == 1 ? QSCALE : 1.0f;
        *(bf16x8*)&dst[t * 8] = cvt8(&src[t * 8], scl);
    } else if (bx < 368) {
        const int t = (bx - 112) * 256 + tid;         // 0..65535
        *(bf16x8*)&hidB[t * 8] = cvt8(&hid[t * 8], 1.0f);
    } else {
        const int z = bx - 368;             // 0..127
        const int kt = z & 15, b = z >> 4;
        for (int x = tid; x < 4096; x += 256) {
            const int r = x >> 6, c = x & 63;
            T[r][c] = hid[((size_t)b * 1024 + kt * 64 + r) * 64 + c];
        }
        __syncthreads();
        const int c  = tid >> 2;
        const int r0 = (tid & 3) * 16;
        short* dst = VtB + ((size_t)b * 64 + c) * 1024 + kt * 64 + r0;
#pragma unroll
        for (int rr = 0; rr < 16; ++rr) dst[rr] = f2bf(T[r0 + rr][c]);
    }
}

// ---------------------------------------------------------------------------
// Kernel 2: Q/K projection as bf16 MFMA GEMM.
// D = w (A) x hid^T (B): D[row=a-local 4g+r][col=s-local qi].
// grid (256, 2): y=0 Q (wqB pre-scaled, bias*QSCALE), y=1 K.
// wave-unit = bx*4+w: s_tile = unit>>1 (16 rows of flat bs), ah = unit&1.
// ---------------------------------------------------------------------------
__global__ __launch_bounds__(256) void qk_gemm(
    const short* __restrict__ hidB,
    const short* __restrict__ wqB, const short* __restrict__ wkB,
    const float* __restrict__ bq,  const float* __restrict__ bk,
    short* __restrict__ Qw, short* __restrict__ Kw)
{
    const short* wB  = blockIdx.y ? wkB : wqB;
    const float* bb  = blockIdx.y ? bk : bq;
    short* outp      = blockIdx.y ? Kw : Qw;
    const float scl  = blockIdx.y ? 1.0f : QSCALE;

    const int tid  = threadIdx.x;
    const int wv   = tid >> 6;
    const int lane = tid & 63;
    const int g  = lane >> 4;
    const int qi = lane & 15;
    const int unit   = blockIdx.x * 4 + wv;
    const int s_tile = unit >> 1;
    const int ah     = unit & 1;

    const int bs = s_tile * 16 + qi;
    const int b = bs >> 10, s = bs & 1023;

    // B operand: hid rows (col = s)
    const short* hrow = hidB + (size_t)bs * 64;
    const bf16x8 hf0 = *(const bf16x8*)(hrow + 8 * g);
    const bf16x8 hf1 = *(const bf16x8*)(hrow + 32 + 8 * g);

#pragma unroll 4
    for (int cc = 0; cc < 16; ++cc) {
        const int ctg = ah * 16 + cc;       // a-tile 0..31
        const short* arow = wB + (size_t)(16 * ctg + qi) * 64;
        const bf16x8 aw0 = *(const bf16x8*)(arow + 8 * g);
        const bf16x8 aw1 = *(const bf16x8*)(arow + 32 + 8 * g);

        const float4 bb4 = *(const float4*)&bb[ctg * 16 + 4 * g];
        f32x4 acc;
        acc[0] = bb4.x * scl; acc[1] = bb4.y * scl;
        acc[2] = bb4.z * scl; acc[3] = bb4.w * scl;
        acc = __builtin_amdgcn_mfma_f32_16x16x32_bf16(aw0, hf0, acc, 0, 0, 0);
        acc = __builtin_amdgcn_mfma_f32_16x16x32_bf16(aw1, hf1, acc, 0, 0, 0);

        const int n  = ctg >> 2;
        const int d0 = 16 * (ctg & 3) + 4 * g;
        bf16x4 ov;
        ov[0] = f2bf(acc[0]); ov[1] = f2bf(acc[1]);
        ov[2] = f2bf(acc[2]); ov[3] = f2bf(acc[3]);
        *(bf16x4*)&outp[(((size_t)b * 8 + n) * 1024 + s) * 64 + d0] = ov;
    }
}

// ---------------------------------------------------------------------------
// Kernel 3: MFMA flash attention — 1 q-tile/wave, 4 blocks/CU.
// grid (16, 8, 8); 256 threads = 4 waves; wave owns q-tile qt = qblk*4+w.
// K/V 64-key tiles staged to LDS (double-buffered, XOR-swizzled).
// Swapped QK^T (q = lane&15, lane-local softmax), PV via O^T = V^T P^T.
// pos folded into MFMA C-init; defer-max (T13, THR=8 in exp2 domain).
// ---------------------------------------------------------------------------
__global__ __launch_bounds__(256, 4) void attn_mfma(
    const short* __restrict__ Qb, const short* __restrict__ Kb,
    const short* __restrict__ VtB,
    const float* __restrict__ posRow, const float* __restrict__ posCol,
    short* __restrict__ hoB)
{
    const int qblk = blockIdx.x;        // 0..15
    const int n  = blockIdx.y;
    const int b  = blockIdx.z;
    const int tid  = threadIdx.x;
    const int w    = tid >> 6;
    const int lane = tid & 63;
    const int g  = lane >> 4;           // 0..3
    const int qi = lane & 15;
    const int qt = qblk * 4 + w;
    const int q  = qt * 16 + qi;
    const int swz = qi & 7;

    __shared__ __align__(16) short Kt[2][4096];   // 16B-chunk swizzled
    __shared__ __align__(16) short Vt[2][4096];

    const short* Qrow = Qb + (((size_t)(b * 8 + n)) * 1024 + q) * 64;
    const bf16x8 qf0 = *(const bf16x8*)(Qrow + 8 * g);
    const bf16x8 qf1 = *(const bf16x8*)(Qrow + 32 + 8 * g);

    float prow[2][4];
    {
        const float* prows = posRow + (n * 32 + (q & 31)) * 32;
#pragma unroll
        for (int c2 = 0; c2 < 2; ++c2)
#pragma unroll
            for (int r = 0; r < 4; ++r)
                prow[c2][r] = prows[16 * c2 + 4 * g + r];
    }
    const float* pcp = posCol + (n * 32 + (qt >> 1)) * 32;

    const short* Kbase = Kb + (((size_t)(b * 8 + n)) * 1024) * 64;
    const short* Vbase = VtB + ((size_t)b * 64) * 1024;

    // staging: thread handles 16B chunks (srow, c16) and (srow+32, c16)
    const int c16 = tid & 7;
    const int srow = tid >> 3;          // 0..31
    const int woffA = srow * 128 + ((c16 ^ (srow & 7)) << 4);
    const int woffB = (srow + 32) * 128 + ((c16 ^ (srow & 7)) << 4);
    const short* kp0 = Kbase + (size_t)srow * 64 + c16 * 8;
    const short* kp1 = Kbase + (size_t)(srow + 32) * 64 + c16 * 8;
    const short* vp0 = Vbase + (size_t)srow * 1024 + c16 * 8;
    const short* vp1 = Vbase + (size_t)(srow + 32) * 1024 + c16 * 8;

    {
        const float4 ka  = *(const float4*)kp0;
        const float4 kb4 = *(const float4*)kp1;
        const float4 va  = *(const float4*)vp0;
        const float4 vb4 = *(const float4*)vp1;
        *(float4*)((char*)&Kt[0][0] + woffA) = ka;
        *(float4*)((char*)&Kt[0][0] + woffB) = kb4;
        *(float4*)((char*)&Vt[0][0] + woffA) = va;
        *(float4*)((char*)&Vt[0][0] + woffB) = vb4;
    }
    __syncthreads();

    float m = -1e30f, lsum = 0.f;
    f32x4 oacc[4];
#pragma unroll
    for (int dt = 0; dt < 4; ++dt) oacc[dt] = (f32x4){0.f, 0.f, 0.f, 0.f};

    int cur = 0;
#pragma unroll 1
    for (int kt = 0; kt < 16; ++kt) {
        // prefetch next tile (latency hides under this tile's compute)
        float4 ka, kb4, va, vb4;
        if (kt < 15) {
            const size_t ko = (size_t)(kt + 1) * 4096;
            const int vo = (kt + 1) * 64;
            ka  = *(const float4*)(kp0 + ko);
            kb4 = *(const float4*)(kp1 + ko);
            va  = *(const float4*)(vp0 + vo);
            vb4 = *(const float4*)(vp1 + vo);
        }

        const char* Ktc = (const char*)&Kt[cur][0];
        const char* Vtc = (const char*)&Vt[cur][0];
        const float pc0 = pcp[2 * kt];
        const float pc1 = pcp[2 * kt + 1];

        // K fragments: row 16ct+qi, chunks g and 4+g (swizzled)
        bf16x8 kf[4][2];
#pragma unroll
        for (int ct = 0; ct < 4; ++ct) {
            const int rb = (16 * ct + qi) * 128;
            kf[ct][0] = *(const bf16x8*)(Ktc + rb + (((g    ) ^ swz) << 4));
            kf[ct][1] = *(const bf16x8*)(Ktc + rb + (((g + 4) ^ swz) << 4));
        }

        // QK^T with pos folded into C-init
        __builtin_amdgcn_s_setprio(1);
        f32x4 sc[4];
#pragma unroll
        for (int ct = 0; ct < 4; ++ct) {
            const float pc = (ct < 2) ? pc0 : pc1;
            f32x4 ci;
#pragma unroll
            for (int r = 0; r < 4; ++r) ci[r] = prow[ct & 1][r] + pc;
            ci = __builtin_amdgcn_mfma_f32_16x16x32_bf16(kf[ct][0], qf0, ci, 0, 0, 0);
            sc[ct] = __builtin_amdgcn_mfma_f32_16x16x32_bf16(kf[ct][1], qf1, ci, 0, 0, 0);
        }
        __builtin_amdgcn_s_setprio(0);

        // V fragments: row 16dt+qi, 8B at chunk 2ct+(g>>1), half g&1
        bf16x4 vf[4][4];
#pragma unroll
        for (int dt = 0; dt < 4; ++dt) {
            const int rb = (16 * dt + qi) * 128;
#pragma unroll
            for (int ct = 0; ct < 4; ++ct)
                vf[ct][dt] = *(const bf16x4*)(Vtc + rb +
                                (((2 * ct + (g >> 1)) ^ swz) << 4) + ((g & 1) * 8));
        }

        // online softmax (exp2 domain) with defer-max
        float tmax = fmaxf(fmaxf(sc[0][0], sc[0][1]), fmaxf(sc[0][2], sc[0][3]));
#pragma unroll
        for (int ct = 1; ct < 4; ++ct)
            tmax = fmaxf(tmax, fmaxf(fmaxf(sc[ct][0], sc[ct][1]),
                                     fmaxf(sc[ct][2], sc[ct][3])));
        tmax = fmaxf(tmax, __shfl_xor(tmax, 16));
        tmax = fmaxf(tmax, __shfl_xor(tmax, 32));

        if (!__all(tmax - m <= 8.0f)) {     // rescale only on real max growth
            const float mnew = fmaxf(m, tmax);
            const float alpha = __builtin_amdgcn_exp2f(m - mnew);
            lsum *= alpha;
#pragma unroll
            for (int dt = 0; dt < 4; ++dt) oacc[dt] *= alpha;
            m = mnew;
        }

        float psum = 0.f;
        bf16x4 pf[4];
#pragma unroll
        for (int ct = 0; ct < 4; ++ct) {
            float p0 = __builtin_amdgcn_exp2f(sc[ct][0] - m);
            float p1 = __builtin_amdgcn_exp2f(sc[ct][1] - m);
            float p2 = __builtin_amdgcn_exp2f(sc[ct][2] - m);
            float p3 = __builtin_amdgcn_exp2f(sc[ct][3] - m);
            psum += (p0 + p1) + (p2 + p3);
            bf16x4 pp;
            pp[0] = f2bf(p0); pp[1] = f2bf(p1); pp[2] = f2bf(p2); pp[3] = f2bf(p3);
            pf[ct] = pp;
        }
        psum += __shfl_xor(psum, 16);
        psum += __shfl_xor(psum, 32);
        lsum += psum;

        // PV: O^T[d][q] += Vt[d][k] * P^T[k][q]
        __builtin_amdgcn_s_setprio(1);
#pragma unroll
        for (int dt = 0; dt < 4; ++dt)
#pragma unroll
            for (int ct = 0; ct < 4; ++ct)
                oacc[dt] = MFMA16(vf[ct][dt], pf[ct], oacc[dt]);
        __builtin_amdgcn_s_setprio(0);

        if (kt < 15) {
            char* Kn = (char*)&Kt[cur ^ 1][0];
            char* Vn = (char*)&Vt[cur ^ 1][0];
            *(float4*)(Kn + woffA) = ka;
            *(float4*)(Kn + woffB) = kb4;
            *(float4*)(Vn + woffA) = va;
            *(float4*)(Vn + woffB) = vb4;
            __syncthreads();
            cur ^= 1;
        }
    }

    // epilogue: bf16 headOut[b][q][n*64 + d], d = 16dt+4g+r
    const float inv = 1.0f / lsum;
    short* orow = hoB + ((size_t)(b * 1024 + q)) * 512 + n * 64;
#pragma unroll
    for (int dt = 0; dt < 4; ++dt) {
        bf16x4 ov;
        ov[0] = f2bf(oacc[dt][0] * inv);
        ov[1] = f2bf(oacc[dt][1] * inv);
        ov[2] = f2bf(oacc[dt][2] * inv);
        ov[3] = f2bf(oacc[dt][3] * inv);
        *(bf16x4*)&orow[16 * dt + 4 * g] = ov;
    }
}

// ---------------------------------------------------------------------------
// Kernel 4: final projection via MFMA.
// C[8192][64] = hoB[8192][512] @ wvB^T;  out[row][d] = C + bv[d].
// ---------------------------------------------------------------------------
__global__ __launch_bounds__(256) void v_proj(
    const short* __restrict__ hoB, const short* __restrict__ wvB,
    const float* __restrict__ bv, float* __restrict__ out)
{
    const int tid  = threadIdx.x;
    const int w    = tid >> 6;
    const int lane = tid & 63;
    const int g  = lane >> 4;
    const int qi = lane & 15;
    const int row0 = blockIdx.x * 64 + w * 16;

    const short* arow = hoB + (size_t)(row0 + qi) * 512 + 8 * g;

    f32x4 acc[4];
#pragma unroll
    for (int ct = 0; ct < 4; ++ct) acc[ct] = (f32x4){0.f, 0.f, 0.f, 0.f};

#pragma unroll 4
    for (int ks = 0; ks < 16; ++ks) {
        const bf16x8 af = *(const bf16x8*)(arow + ks * 32);
#pragma unroll
        for (int ct = 0; ct < 4; ++ct) {
            const bf16x8 bfr = *(const bf16x8*)(wvB + (size_t)(16 * ct + qi) * 512 + ks * 32 + 8 * g);
            acc[ct] = __builtin_amdgcn_mfma_f32_16x16x32_bf16(af, bfr, acc[ct], 0, 0, 0);
        }
    }

#pragma unroll
    for (int ct = 0; ct < 4; ++ct) {
        const float bias = bv[16 * ct + qi];
#pragma unroll
        for (int r = 0; r < 4; ++r)
            out[(size_t)(row0 + 4 * g + r) * 64 + 16 * ct + qi] = acc[ct][r] + bias;
    }
}

// ---------------------------------------------------------------------------
extern "C" void kernel_launch(void* const* d_in, const int* in_sizes, int n_in,
                              void* d_out, int out_size, void* d_ws, size_t ws_size,
                              hipStream_t stream)
{
    const float* hid     = (const float*)d_in[0];
    const float* row_emb = (const float*)d_in[2];
    const float* col_emb = (const float*)d_in[3];
    const float* w_row   = (const float*)d_in[4];
    const float* w_col   = (const float*)d_in[5];
    const float* w_q     = (const float*)d_in[6];
    const float* b_q     = (const float*)d_in[7];
    const float* w_k     = (const float*)d_in[8];
    const float* b_k     = (const float*)d_in[9];
    const float* w_v     = (const float*)d_in[10];
    const float* b_v     = (const float*)d_in[11];
    float* out = (float*)d_out;

    // ws layout (shorts unless noted):
    // Qw 4M | Kw 4M | VtB 512K | posRow 8K f32 | posCol 8K f32 |
    // wvB 32K | wqB 32K | wkB 32K | hidB 512K | hoB 4M
    short* Qw     = (short*)d_ws;
    short* Kw     = Qw + (size_t)SB * SNH * SS * SC;
    short* VtB    = Kw + (size_t)SB * SNH * SS * SC;
    float* posRow = (float*)(VtB + (size_t)SB * SC * SS);
    float* posCol = posRow + SNH * 32 * 32;
    short* wvB    = (short*)(posCol + SNH * 32 * 32);
    short* wqB    = wvB + (size_t)SC * SNH * SC;
    short* wkB    = wqB + (size_t)SNH * SC * SC;
    short* hidB   = wkB + (size_t)SNH * SC * SC;
    short* hoB    = hidB + (size_t)SB * SS * SC;

    prep<<<496, 256, 0, stream>>>(row_emb, col_emb, w_row, w_col, w_v, w_q, w_k,
                                  hid, posRow, posCol, wvB, wqB, wkB, hidB, VtB);
    qk_gemm<<<dim3(256, 2), 256, 0, stream>>>(hidB, wqB, wkB, b_q, b_k, Qw, Kw);
    attn_mfma<<<dim3(16, 8, 8), 256, 0, stream>>>(Qw, Kw, VtB, posRow, posCol, hoB);
    v_proj<<<128, 256, 0, stream>>>(hoB, wvB, b_v, out);
}